// Round 1
// baseline (311.491 us; speedup 1.0000x reference)
//
#include <hip/hip_runtime.h>

#define NFFT 16000   // 128 * 125
#define BATCH 128
#define DIM 2048

__device__ __forceinline__ float2 cmul(float2 a, float2 b) {
    return make_float2(a.x * b.x - a.y * b.y, a.x * b.y + a.y * b.x);
}
__device__ __forceinline__ float2 cadd(float2 a, float2 b) { return make_float2(a.x + b.x, a.y + b.y); }
__device__ __forceinline__ float2 csub(float2 a, float2 b) { return make_float2(a.x - b.x, a.y - b.y); }
__device__ __forceinline__ float2 cis(float ang) { return make_float2(__cosf(ang), __sinf(ang)); }

__device__ __forceinline__ int rev5_3(int n) {
    int d0 = n % 5, r = n / 5;
    int d1 = r % 5, d2 = r / 5;
    return d0 * 25 + d1 * 5 + d2;
}
__device__ __forceinline__ int rev7(int x) { return (int)(__brev((unsigned)x) >> 25); }

__device__ __forceinline__ float2 shfl2(float2 v, int lane) {
    return make_float2(__shfl(v.x, lane), __shfl(v.y, lane));
}
__device__ __forceinline__ float2 shfl2_xor(float2 v, int mask) {
    return make_float2(__shfl_xor(v.x, mask), __shfl_xor(v.y, mask));
}

// packed-spectrum pointwise: conj(G)[k] given Zk=Z[k], Zm=Z[N-k]
__device__ __forceinline__ float2 conjG(float2 Zk, float2 Zm) {
    float u = (Zk.x * Zk.x - Zk.y * Zk.y) - (Zm.x * Zm.x - Zm.y * Zm.y);
    float v = 2.f * (Zk.x * Zk.y + Zm.x * Zm.y);
    return make_float2(0.25f * v, 0.25f * u);
}

// in-register 128-point DIF FFT across one wave; twiddles hoisted (lane-only).
// lane l holds positions l (x0), l+64 (x1); output: x0=X[rev7(l)], x1=X[rev7(l)+1]
__device__ __forceinline__ void dif128(float2& x0, float2& x1, const float2* tw, int l) {
    {   // stage m=64 (register-local)
        float2 a = x0, b = x1;
        x0 = cadd(a, b);
        x1 = cmul(csub(a, b), tw[0]);
    }
    int s = 1;
    #pragma unroll
    for (int m = 32; m >= 1; m >>= 1, ++s) {
        float2 w = tw[s];
        float2 o0 = shfl2_xor(x0, m), o1 = shfl2_xor(x1, m);
        if (l & m) {
            x0 = cmul(csub(o0, x0), w);
            x1 = cmul(csub(o1, x1), w);
        } else {
            x0 = cadd(x0, o0);
            x1 = cadd(x1, o1);
        }
    }
}

// ---- find the single nonzero (idx, sign) in each row of C1/C2 (unchanged, verified) ----
__global__ void extract_sketch(const float* __restrict__ C1, const float* __restrict__ C2,
                               int* __restrict__ idx1, float* __restrict__ sgn1,
                               int* __restrict__ idx2, float* __restrict__ sgn2) {
    int gwave = (blockIdx.x * blockDim.x + threadIdx.x) >> 6;
    int lane = threadIdx.x & 63;
    if (gwave >= 2 * DIM) return;
    const float* row;
    int* idxp; float* sgnp; int d;
    if (gwave < DIM) { d = gwave;       row = C1 + (size_t)d * NFFT; idxp = idx1; sgnp = sgn1; }
    else             { d = gwave - DIM; row = C2 + (size_t)d * NFFT; idxp = idx2; sgnp = sgn2; }
    for (int step = 0; step < 16; ++step) {
        int off0 = step * 1024 + lane * 4;
        float4 v[4];
        #pragma unroll
        for (int c = 0; c < 4; ++c) {
            int off = off0 + c * 256;
            v[c] = (off < NFFT) ? *reinterpret_cast<const float4*>(row + off)
                                : make_float4(0.f, 0.f, 0.f, 0.f);
        }
        bool found = false;
        #pragma unroll
        for (int c = 0; c < 4; ++c) {
            float4 w = v[c];
            if (w.x != 0.f || w.y != 0.f || w.z != 0.f || w.w != 0.f) {
                int off = off0 + c * 256;
                int j; float s;
                if (w.x != 0.f)      { j = 0; s = w.x; }
                else if (w.y != 0.f) { j = 1; s = w.y; }
                else if (w.z != 0.f) { j = 2; s = w.z; }
                else                 { j = 3; s = w.w; }
                idxp[d] = off + j;
                sgnp[d] = s;
                found = true;
            }
        }
        if (__any(found)) return;
    }
}

// ---- fused k1+k2+k3: whole 16000-pt packed FFT pipeline in one 128 KB LDS buffer ----
// One block per batch. LDS layout by phase (A has row stride 125 float2):
//   P1/P2:  A[n1*125 + s]    s = rev5_3(n2) scatter, then DIT-5^3 over n2 -> natural k2
//   P3:     per-wave column pair (c, 125-c): read A[n1*125+c] (fold W_N^{n1*c}),
//           dif128 fwd, pointwise conjG, re-permute, dif128 (inverse start),
//           fold W_N^{c*e}, write back IN PLACE: A[e*125 + c]  (now [j1][m1])
//   P4:     DIF-5^3 over m1 (contiguous!), natural input -> digit-reversed output
//   P5:     out[j1 + 128*rev5_3(s)] = A[j1*125+s].x / N
__global__ void __launch_bounds__(1024) fused_fft(
        const float* __restrict__ x1, const float* __restrict__ x2,
        const int* __restrict__ idx1, const float* __restrict__ sgn1,
        const int* __restrict__ idx2, const float* __restrict__ sgn2,
        float* __restrict__ out) {
    __shared__ float2 A[16000];          // 128000 B
    const int b = blockIdx.x;
    const int tid = threadIdx.x;

    // P0: zero
    for (int i = tid; i < 16000; i += 1024) A[i] = make_float2(0.f, 0.f);
    __syncthreads();

    // P1: scatter z = sgn1*x1 + i*sgn2*x2
    const float* x1b = x1 + (size_t)b * DIM;
    const float* x2b = x2 + (size_t)b * DIM;
    for (int d = tid; d < DIM; d += 1024) {
        int p1 = idx1[d];
        atomicAdd(&A[(p1 & 127) * 125 + rev5_3(p1 >> 7)].x, sgn1[d] * x1b[d]);
        int p2 = idx2[d];
        atomicAdd(&A[(p2 & 127) * 125 + rev5_3(p2 >> 7)].y, sgn2[d] * x2b[d]);
    }
    __syncthreads();

    const float C1_5 = 0.30901699437494742f, S1_5 = 0.95105651629515357f;
    const float C2_5 = -0.80901699437494745f, S2_5 = 0.58778525229247312f;
    const float2 w5tab[5] = { make_float2(1.f, 0.f),
                              make_float2(C1_5, -S1_5), make_float2(C2_5, -S2_5),
                              make_float2(C2_5,  S2_5), make_float2(C1_5,  S1_5) };

    // P2: 128 x (125-pt DIT over n2), rev-ordered input -> natural k2. In place.
    #pragma unroll
    for (int s = 0; s < 3; ++s) {
        const int m = (s == 0) ? 1 : (s == 1) ? 5 : 25;
        const float angstep = -6.28318530717958647692f / (float)(5 * m);
        for (int task = tid; task < 128 * 25; task += 1024) {
            int row = task / 25;
            int bf = task - row * 25;
            int t = bf % m, blk = bf / m;
            int base = row * 125 + blk * (5 * m) + t;
            float2 xv[5];
            #pragma unroll
            for (int r = 0; r < 5; ++r) xv[r] = A[base + r * m];
            if (m > 1) {
                float2 w1 = cis(angstep * (float)t);
                float2 w2 = cmul(w1, w1), w3 = cmul(w2, w1), w4 = cmul(w2, w2);
                xv[1] = cmul(xv[1], w1); xv[2] = cmul(xv[2], w2);
                xv[3] = cmul(xv[3], w3); xv[4] = cmul(xv[4], w4);
            }
            float2 y[5];
            #pragma unroll
            for (int qq = 0; qq < 5; ++qq) {
                float2 acc = xv[0];
                #pragma unroll
                for (int r = 1; r < 5; ++r) {
                    float2 t2 = cmul(xv[r], w5tab[(qq * r) % 5]);
                    acc.x += t2.x; acc.y += t2.y;
                }
                y[qq] = acc;
            }
            #pragma unroll
            for (int qq = 0; qq < 5; ++qq) A[base + qq * m] = y[qq];
        }
        __syncthreads();
    }

    // P3: per-wave column pairs, in place (each task owns columns {c, 125-c}).
    const int w = tid >> 6, l = tid & 63;
    const float PI_F = 3.14159265358979323846f;
    const float ANGN = -6.28318530717958647692f / 16000.0f;

    float2 tw[7];
    tw[0] = cis(-PI_F / 64.0f * (float)l);
    {
        int m = 32;
        #pragma unroll
        for (int s = 1; s < 7; ++s, m >>= 1)
            tw[s] = cis(-PI_F / (float)m * (float)(l & (m - 1)));
    }

    for (int tsk = w; tsk < 63; tsk += 16) {
        const int c = tsk, cm = tsk ? 125 - tsk : 0;

        // reads (fold inter-dim twiddle W_N^{n1*k2} here; k1 used to apply it at U-write)
        float2 a0 = cmul(A[l * 125 + c],        cis(ANGN * (float)(l * c)));
        float2 a1 = cmul(A[(l + 64) * 125 + c], cis(ANGN * (float)((l + 64) * c)));
        dif128(a0, a1, tw, l);
        float2 b0, b1;
        if (tsk) {
            b0 = cmul(A[l * 125 + cm],        cis(ANGN * (float)(l * cm)));
            b1 = cmul(A[(l + 64) * 125 + cm], cis(ANGN * (float)((l + 64) * cm)));
            dif128(b0, b1, tw, l);
        }

        const int e  = rev7(l);           // even; lane holds rows e, e+1
        const int lp = rev7(126 - e);     // holder lane of rows 126-e (reg0) / 127-e (reg1)

        float2 gA0, gA1, gB0, gB1;
        if (tsk) {
            float2 zm0 = shfl2(b1, lp);   // Zcm[127-e]
            float2 zm1 = shfl2(b0, lp);   // Zcm[126-e]
            gA0 = conjG(a0, zm0);
            gA1 = conjG(a1, zm1);
            float2 ym0 = shfl2(a1, lp);   // Zc[127-e]
            float2 ym1 = shfl2(a0, lp);   // Zc[126-e]
            gB0 = conjG(b0, ym0);
            gB1 = conjG(b1, ym1);
        } else {
            int hz = rev7((128 - e) & 127);
            float2 zm0 = shfl2(a0, hz);   // Z0[(128-e)&127]
            float2 zm1 = shfl2(a1, lp);   // Z0[127-e]
            gA0 = conjG(a0, zm0);
            gA1 = conjG(a1, zm1);
            gB0 = gB1 = make_float2(0.f, 0.f);
        }

        const int q = rev7(l & 62);
        {
            float2 t00 = shfl2(gA0, q),     t10 = shfl2(gA1, q);
            float2 t01 = shfl2(gA0, q + 1), t11 = shfl2(gA1, q + 1);
            float2 p0 = (l & 1) ? t10 : t00;
            float2 p1 = (l & 1) ? t11 : t01;
            dif128(p0, p1, tw, l);
            p0 = cmul(p0, cis(ANGN * (float)(c * e)));
            p1 = cmul(p1, cis(ANGN * (float)(c * (e + 1))));
            A[e * 125 + c] = p0;          // V[m1=c][j1=e] at A[j1*125+m1]
            A[(e + 1) * 125 + c] = p1;
        }
        if (tsk) {
            float2 t00 = shfl2(gB0, q),     t10 = shfl2(gB1, q);
            float2 t01 = shfl2(gB0, q + 1), t11 = shfl2(gB1, q + 1);
            float2 p0 = (l & 1) ? t10 : t00;
            float2 p1 = (l & 1) ? t11 : t01;
            dif128(p0, p1, tw, l);
            p0 = cmul(p0, cis(ANGN * (float)(cm * e)));
            p1 = cmul(p1, cis(ANGN * (float)(cm * (e + 1))));
            A[e * 125 + cm] = p0;
            A[(e + 1) * 125 + cm] = p1;
        }
    }
    __syncthreads();

    // P4: 128 x (125-pt DIF over m1, contiguous), natural input -> digit-reversed out.
    // Stage (L, m=L/5): y[q] = sum_r x[base+r*m]*w5^{qr}; y[q] *= W_L^{t*q}; store base+q*m.
    #pragma unroll
    for (int s = 0; s < 3; ++s) {
        const int L = (s == 0) ? 125 : (s == 1) ? 25 : 5;
        const int m = L / 5;
        const float angstep = -6.28318530717958647692f / (float)L;
        for (int task = tid; task < 128 * 25; task += 1024) {
            int row = task / 25;
            int bf = task - row * 25;
            int t = bf % m, blk = bf / m;
            int base = row * 125 + blk * L + t;
            float2 xv[5];
            #pragma unroll
            for (int r = 0; r < 5; ++r) xv[r] = A[base + r * m];
            float2 y[5];
            #pragma unroll
            for (int qq = 0; qq < 5; ++qq) {
                float2 acc = xv[0];
                #pragma unroll
                for (int r = 1; r < 5; ++r) {
                    float2 t2 = cmul(xv[r], w5tab[(qq * r) % 5]);
                    acc.x += t2.x; acc.y += t2.y;
                }
                y[qq] = acc;
            }
            if (L > 5) {
                float2 w1 = cis(angstep * (float)t);
                float2 w2 = cmul(w1, w1), w3 = cmul(w2, w1), w4 = cmul(w2, w2);
                y[1] = cmul(y[1], w1); y[2] = cmul(y[2], w2);
                y[3] = cmul(y[3], w3); y[4] = cmul(y[4], w4);
            }
            #pragma unroll
            for (int qq = 0; qq < 5; ++qq) A[base + qq * m] = y[qq];
        }
        __syncthreads();
    }

    // P5: output; slot s holds X[j2 = rev5_3(s)]
    const float invN = 1.0f / (float)NFFT;
    float* outb = out + (size_t)b * NFFT;
    for (int i = tid; i < 16000; i += 1024) {
        int j1 = i & 127, s = i >> 7;
        outb[j1 + 128 * rev5_3(s)] = A[j1 * 125 + s].x * invN;
    }
}

extern "C" void kernel_launch(void* const* d_in, const int* in_sizes, int n_in,
                              void* d_out, int out_size, void* d_ws, size_t ws_size,
                              hipStream_t stream) {
    (void)in_sizes; (void)n_in; (void)out_size; (void)ws_size;
    const float* x1 = (const float*)d_in[0];
    const float* x2 = (const float*)d_in[1];
    const float* C1 = (const float*)d_in[2];
    const float* C2 = (const float*)d_in[3];
    float* out = (float*)d_out;

    char* w = (char*)d_ws;
    int*    idx1 = (int*)  (w);                       // 8 KB
    float*  sgn1 = (float*)(w + 8192);                // 8 KB
    int*    idx2 = (int*)  (w + 16384);               // 8 KB
    float*  sgn2 = (float*)(w + 24576);               // 8 KB

    extract_sketch<<<(2 * DIM) / 4, 256, 0, stream>>>(C1, C2, idx1, sgn1, idx2, sgn2);
    fused_fft     <<<BATCH, 1024, 0, stream>>>(x1, x2, idx1, sgn1, idx2, sgn2, out);
}

// Round 2
// 310.691 us; speedup vs baseline: 1.0026x; 1.0026x over previous
//
#include <hip/hip_runtime.h>

#define NFFT 16000   // 128 * 125
#define BATCH 128
#define DIM 2048

__device__ __forceinline__ float2 cmul(float2 a, float2 b) {
    return make_float2(a.x * b.x - a.y * b.y, a.x * b.y + a.y * b.x);
}
__device__ __forceinline__ float2 cadd(float2 a, float2 b) { return make_float2(a.x + b.x, a.y + b.y); }
__device__ __forceinline__ float2 csub(float2 a, float2 b) { return make_float2(a.x - b.x, a.y - b.y); }
__device__ __forceinline__ float2 cis(float ang) { return make_float2(__cosf(ang), __sinf(ang)); }

__device__ __forceinline__ int rev5_3(int n) {
    int d0 = n % 5, r = n / 5;
    int d1 = r % 5, d2 = r / 5;
    return d0 * 25 + d1 * 5 + d2;
}
__device__ __forceinline__ int rev7(int x) { return (int)(__brev((unsigned)x) >> 25); }

__device__ __forceinline__ float2 shfl2(float2 v, int lane) {
    return make_float2(__shfl(v.x, lane), __shfl(v.y, lane));
}
__device__ __forceinline__ float2 shfl2_xor(float2 v, int mask) {
    return make_float2(__shfl_xor(v.x, mask), __shfl_xor(v.y, mask));
}

// packed-spectrum pointwise: conj(G)[k] given Zk=Z[k], Zm=Z[N-k]
__device__ __forceinline__ float2 conjG(float2 Zk, float2 Zm) {
    float u = (Zk.x * Zk.x - Zk.y * Zk.y) - (Zm.x * Zm.x - Zm.y * Zm.y);
    float v = 2.f * (Zk.x * Zk.y + Zm.x * Zm.y);
    return make_float2(0.25f * v, 0.25f * u);
}

// in-register 128-point DIF FFT across one wave; twiddles hoisted (lane-only).
// lane l holds positions l (x0), l+64 (x1); output: x0=X[rev7(l)], x1=X[rev7(l)+1]
__device__ __forceinline__ void dif128(float2& x0, float2& x1, const float2* tw, int l) {
    {   // stage m=64 (register-local)
        float2 a = x0, b = x1;
        x0 = cadd(a, b);
        x1 = cmul(csub(a, b), tw[0]);
    }
    int s = 1;
    #pragma unroll
    for (int m = 32; m >= 1; m >>= 1, ++s) {
        float2 w = tw[s];
        float2 o0 = shfl2_xor(x0, m), o1 = shfl2_xor(x1, m);
        if (l & m) {
            x0 = cmul(csub(o0, x0), w);
            x1 = cmul(csub(o1, x1), w);
        } else {
            x0 = cadd(x0, o0);
            x1 = cadd(x1, o1);
        }
    }
}

// ---- find the single nonzero (idx, sign) in each row of C1/C2 (unchanged, verified) ----
__global__ void extract_sketch(const float* __restrict__ C1, const float* __restrict__ C2,
                               int* __restrict__ idx1, float* __restrict__ sgn1,
                               int* __restrict__ idx2, float* __restrict__ sgn2) {
    int gwave = (blockIdx.x * blockDim.x + threadIdx.x) >> 6;
    int lane = threadIdx.x & 63;
    if (gwave >= 2 * DIM) return;
    const float* row;
    int* idxp; float* sgnp; int d;
    if (gwave < DIM) { d = gwave;       row = C1 + (size_t)d * NFFT; idxp = idx1; sgnp = sgn1; }
    else             { d = gwave - DIM; row = C2 + (size_t)d * NFFT; idxp = idx2; sgnp = sgn2; }
    for (int step = 0; step < 16; ++step) {
        int off0 = step * 1024 + lane * 4;
        float4 v[4];
        #pragma unroll
        for (int c = 0; c < 4; ++c) {
            int off = off0 + c * 256;
            v[c] = (off < NFFT) ? *reinterpret_cast<const float4*>(row + off)
                                : make_float4(0.f, 0.f, 0.f, 0.f);
        }
        bool found = false;
        #pragma unroll
        for (int c = 0; c < 4; ++c) {
            float4 w = v[c];
            if (w.x != 0.f || w.y != 0.f || w.z != 0.f || w.w != 0.f) {
                int off = off0 + c * 256;
                int j; float s;
                if (w.x != 0.f)      { j = 0; s = w.x; }
                else if (w.y != 0.f) { j = 1; s = w.y; }
                else if (w.z != 0.f) { j = 2; s = w.z; }
                else                 { j = 3; s = w.w; }
                idxp[d] = off + j;
                sgnp[d] = s;
                found = true;
            }
        }
        if (__any(found)) return;
    }
}

// ---- K_A: scatter + 125-pt column FFTs (over n2) + inter-dim twiddle, full GPU ----
// grid = 128 b x 2 halves, 1024 threads, 64 KB LDS.
// writes U[b][n1*125 + k2] = S[n1][k2] * W_N^{n1*k2}   (row-major, twiddle folded)
__global__ void __launch_bounds__(1024) k1_colfft(
        const float* __restrict__ x1, const float* __restrict__ x2,
        const int* __restrict__ idx1, const float* __restrict__ sgn1,
        const int* __restrict__ idx2, const float* __restrict__ sgn2,
        float2* __restrict__ U) {
    __shared__ float2 S[64 * 125];       // 64,000 B
    const int b = blockIdx.x >> 1, h = blockIdx.x & 1;
    const int tid = threadIdx.x;

    for (int i = tid; i < 64 * 125; i += 1024) S[i] = make_float2(0.f, 0.f);
    __syncthreads();

    const float* x1b = x1 + (size_t)b * DIM;
    const float* x2b = x2 + (size_t)b * DIM;
    for (int d = tid; d < DIM; d += 1024) {
        int p1 = idx1[d]; int n1a = p1 & 127;
        if ((n1a >> 6) == h) atomicAdd(&S[(n1a & 63) * 125 + rev5_3(p1 >> 7)].x, sgn1[d] * x1b[d]);
        int p2 = idx2[d]; int n1b = p2 & 127;
        if ((n1b >> 6) == h) atomicAdd(&S[(n1b & 63) * 125 + rev5_3(p2 >> 7)].y, sgn2[d] * x2b[d]);
    }
    __syncthreads();

    const float C1_5 = 0.30901699437494742f, S1_5 = 0.95105651629515357f;
    const float C2_5 = -0.80901699437494745f, S2_5 = 0.58778525229247312f;
    const float2 w5tab[5] = { make_float2(1.f, 0.f),
                              make_float2(C1_5, -S1_5), make_float2(C2_5, -S2_5),
                              make_float2(C2_5,  S2_5), make_float2(C1_5,  S1_5) };
    #pragma unroll
    for (int s = 0; s < 3; ++s) {
        const int m = (s == 0) ? 1 : (s == 1) ? 5 : 25;
        const float angstep = -6.28318530717958647692f / (float)(5 * m);
        for (int task = tid; task < 64 * 25; task += 1024) {
            int row = task / 25;
            int bf = task - row * 25;
            int t = bf % m, blk = bf / m;
            int base = row * 125 + blk * (5 * m) + t;
            float2 xv[5];
            #pragma unroll
            for (int r = 0; r < 5; ++r) xv[r] = S[base + r * m];
            if (m > 1) {
                float2 w1 = cis(angstep * (float)t);
                float2 w2 = cmul(w1, w1), w3 = cmul(w2, w1), w4 = cmul(w2, w2);
                xv[1] = cmul(xv[1], w1); xv[2] = cmul(xv[2], w2);
                xv[3] = cmul(xv[3], w3); xv[4] = cmul(xv[4], w4);
            }
            float2 y[5];
            #pragma unroll
            for (int qq = 0; qq < 5; ++qq) {
                float2 acc = xv[0];
                #pragma unroll
                for (int r = 1; r < 5; ++r) {
                    float2 t2 = cmul(xv[r], w5tab[(qq * r) % 5]);
                    acc.x += t2.x; acc.y += t2.y;
                }
                y[qq] = acc;
            }
            #pragma unroll
            for (int qq = 0; qq < 5; ++qq) S[base + qq * m] = y[qq];
        }
        __syncthreads();
    }

    const float ANGN = -6.28318530717958647692f / 16000.0f;
    float2* Ub = U + (size_t)b * NFFT;
    // k2-fast store: contiguous global writes, contiguous LDS reads
    for (int i = tid; i < 64 * 125; i += 1024) {
        int n1l = i / 125, k2 = i - n1l * 125;
        int n1 = h * 64 + n1l;
        Ub[n1 * 125 + k2] = cmul(S[i], cis(ANGN * (float)(n1 * k2)));
    }
}

// ---- K_B: bulk-load U -> LDS, then P3 (128-pt column FFT pairs + pointwise +
//      inverse-start) in place, P4 (125-pt row DIF), P5 (real store). ----
// grid = 128 (one block per batch), 1024 threads, 128 KB LDS.
// A layout throughout: A[row*125 + col]; P3 reads/writes columns in place.
__global__ void __launch_bounds__(1024) k2_fused(const float2* __restrict__ U,
                                                 float* __restrict__ out) {
    __shared__ __align__(16) float2 A[16000];    // 128,000 B
    const int b = blockIdx.x;
    const int tid = threadIdx.x;

    // bulk coalesced copy U[b] -> A (same [n1][k2] layout, twiddle already folded)
    {
        const float4* src = reinterpret_cast<const float4*>(U + (size_t)b * NFFT);
        float4* dst = reinterpret_cast<float4*>(A);
        for (int i = tid; i < 8000; i += 1024) dst[i] = src[i];
    }
    __syncthreads();

    const int w = tid >> 6, l = tid & 63;
    const float PI_F = 3.14159265358979323846f;
    const float ANGN = -6.28318530717958647692f / 16000.0f;

    float2 tw[7];
    tw[0] = cis(-PI_F / 64.0f * (float)l);
    {
        int m = 32;
        #pragma unroll
        for (int s = 1; s < 7; ++s, m >>= 1)
            tw[s] = cis(-PI_F / (float)m * (float)(l & (m - 1)));
    }

    // P3: per-wave column pairs {c, 125-c}, in place (disjoint column ownership)
    for (int tsk = w; tsk < 63; tsk += 16) {
        const int c = tsk, cm = tsk ? 125 - tsk : 0;

        float2 a0 = A[l * 125 + c];
        float2 a1 = A[(l + 64) * 125 + c];
        dif128(a0, a1, tw, l);
        float2 b0, b1;
        if (tsk) {
            b0 = A[l * 125 + cm];
            b1 = A[(l + 64) * 125 + cm];
            dif128(b0, b1, tw, l);
        }

        const int e  = rev7(l);           // even; lane holds rows e, e+1
        const int lp = rev7(126 - e);     // holder lane of rows 126-e (reg0) / 127-e (reg1)

        float2 gA0, gA1, gB0, gB1;
        if (tsk) {
            float2 zm0 = shfl2(b1, lp);   // Zcm[127-e]
            float2 zm1 = shfl2(b0, lp);   // Zcm[126-e]
            gA0 = conjG(a0, zm0);
            gA1 = conjG(a1, zm1);
            float2 ym0 = shfl2(a1, lp);   // Zc[127-e]
            float2 ym1 = shfl2(a0, lp);   // Zc[126-e]
            gB0 = conjG(b0, ym0);
            gB1 = conjG(b1, ym1);
        } else {
            int hz = rev7((128 - e) & 127);
            float2 zm0 = shfl2(a0, hz);   // Z0[(128-e)&127]
            float2 zm1 = shfl2(a1, lp);   // Z0[127-e]
            gA0 = conjG(a0, zm0);
            gA1 = conjG(a1, zm1);
            gB0 = gB1 = make_float2(0.f, 0.f);
        }

        const int q = rev7(l & 62);
        {
            float2 t00 = shfl2(gA0, q),     t10 = shfl2(gA1, q);
            float2 t01 = shfl2(gA0, q + 1), t11 = shfl2(gA1, q + 1);
            float2 p0 = (l & 1) ? t10 : t00;
            float2 p1 = (l & 1) ? t11 : t01;
            dif128(p0, p1, tw, l);
            p0 = cmul(p0, cis(ANGN * (float)(c * e)));
            p1 = cmul(p1, cis(ANGN * (float)(c * (e + 1))));
            A[e * 125 + c] = p0;          // V[m1=c][j1=e] at A[j1*125+m1]
            A[(e + 1) * 125 + c] = p1;
        }
        if (tsk) {
            float2 t00 = shfl2(gB0, q),     t10 = shfl2(gB1, q);
            float2 t01 = shfl2(gB0, q + 1), t11 = shfl2(gB1, q + 1);
            float2 p0 = (l & 1) ? t10 : t00;
            float2 p1 = (l & 1) ? t11 : t01;
            dif128(p0, p1, tw, l);
            p0 = cmul(p0, cis(ANGN * (float)(cm * e)));
            p1 = cmul(p1, cis(ANGN * (float)(cm * (e + 1))));
            A[e * 125 + cm] = p0;
            A[(e + 1) * 125 + cm] = p1;
        }
    }
    __syncthreads();

    const float C1_5 = 0.30901699437494742f, S1_5 = 0.95105651629515357f;
    const float C2_5 = -0.80901699437494745f, S2_5 = 0.58778525229247312f;
    const float2 w5tab[5] = { make_float2(1.f, 0.f),
                              make_float2(C1_5, -S1_5), make_float2(C2_5, -S2_5),
                              make_float2(C2_5,  S2_5), make_float2(C1_5,  S1_5) };

    // P4: 128 x (125-pt DIF over m1, contiguous), natural input -> digit-reversed out.
    #pragma unroll
    for (int s = 0; s < 3; ++s) {
        const int L = (s == 0) ? 125 : (s == 1) ? 25 : 5;
        const int m = L / 5;
        const float angstep = -6.28318530717958647692f / (float)L;
        for (int task = tid; task < 128 * 25; task += 1024) {
            int row = task / 25;
            int bf = task - row * 25;
            int t = bf % m, blk = bf / m;
            int base = row * 125 + blk * L + t;
            float2 xv[5];
            #pragma unroll
            for (int r = 0; r < 5; ++r) xv[r] = A[base + r * m];
            float2 y[5];
            #pragma unroll
            for (int qq = 0; qq < 5; ++qq) {
                float2 acc = xv[0];
                #pragma unroll
                for (int r = 1; r < 5; ++r) {
                    float2 t2 = cmul(xv[r], w5tab[(qq * r) % 5]);
                    acc.x += t2.x; acc.y += t2.y;
                }
                y[qq] = acc;
            }
            if (L > 5) {
                float2 w1 = cis(angstep * (float)t);
                float2 w2 = cmul(w1, w1), w3 = cmul(w2, w1), w4 = cmul(w2, w2);
                y[1] = cmul(y[1], w1); y[2] = cmul(y[2], w2);
                y[3] = cmul(y[3], w3); y[4] = cmul(y[4], w4);
            }
            #pragma unroll
            for (int qq = 0; qq < 5; ++qq) A[base + qq * m] = y[qq];
        }
        __syncthreads();
    }

    // P5: output; slot s holds X[j2 = rev5_3(s)]
    const float invN = 1.0f / (float)NFFT;
    float* outb = out + (size_t)b * NFFT;
    for (int i = tid; i < 16000; i += 1024) {
        int j1 = i & 127, s = i >> 7;
        outb[j1 + 128 * rev5_3(s)] = A[j1 * 125 + s].x * invN;
    }
}

extern "C" void kernel_launch(void* const* d_in, const int* in_sizes, int n_in,
                              void* d_out, int out_size, void* d_ws, size_t ws_size,
                              hipStream_t stream) {
    (void)in_sizes; (void)n_in; (void)out_size; (void)ws_size;
    const float* x1 = (const float*)d_in[0];
    const float* x2 = (const float*)d_in[1];
    const float* C1 = (const float*)d_in[2];
    const float* C2 = (const float*)d_in[3];
    float* out = (float*)d_out;

    char* w = (char*)d_ws;
    int*    idx1 = (int*)  (w);                       // 8 KB
    float*  sgn1 = (float*)(w + 8192);                // 8 KB
    int*    idx2 = (int*)  (w + 16384);               // 8 KB
    float*  sgn2 = (float*)(w + 24576);               // 8 KB
    float2* U    = (float2*)(w + 32768);              // 16.384 MB

    extract_sketch<<<(2 * DIM) / 4, 256, 0, stream>>>(C1, C2, idx1, sgn1, idx2, sgn2);
    k1_colfft     <<<BATCH * 2, 1024, 0, stream>>>(x1, x2, idx1, sgn1, idx2, sgn2, U);
    k2_fused      <<<BATCH, 1024, 0, stream>>>(U, out);
}

// Round 3
// 297.141 us; speedup vs baseline: 1.0483x; 1.0456x over previous
//
#include <hip/hip_runtime.h>

#define NFFT 16000   // 128 * 125
#define BATCH 128
#define DIM 2048
#define TP 17        // padded LDS row stride in K3

__device__ __forceinline__ float2 cmul(float2 a, float2 b) {
    return make_float2(a.x * b.x - a.y * b.y, a.x * b.y + a.y * b.x);
}
__device__ __forceinline__ float2 cadd(float2 a, float2 b) { return make_float2(a.x + b.x, a.y + b.y); }
__device__ __forceinline__ float2 csub(float2 a, float2 b) { return make_float2(a.x - b.x, a.y - b.y); }
__device__ __forceinline__ float2 cis(float ang) { return make_float2(__cosf(ang), __sinf(ang)); }

__device__ __forceinline__ int rev5_3(int n) {
    int d0 = n % 5, r = n / 5;
    int d1 = r % 5, d2 = r / 5;
    return d0 * 25 + d1 * 5 + d2;
}
__device__ __forceinline__ int rev7(int x) { return (int)(__brev((unsigned)x) >> 25); }

__device__ __forceinline__ float2 shfl2(float2 v, int lane) {
    return make_float2(__shfl(v.x, lane), __shfl(v.y, lane));
}

// ---- VALU lane-exchange helpers (bit-exact replacements for __shfl_xor) ----
// DPP: quad_perm for xor1/xor2, row_ror:8 for xor8 (ror8==xor8 within a 16-row).
template<int CTRL>
__device__ __forceinline__ float dpp_mov(float v) {
    int i = __builtin_bit_cast(int, v);
    i = __builtin_amdgcn_update_dpp(i, i, CTRL, 0xF, 0xF, false);
    return __builtin_bit_cast(float, i);
}

#if __has_builtin(__builtin_amdgcn_permlane16_swap)
__device__ __forceinline__ float xchg16f(float v) {
    unsigned u = __builtin_bit_cast(unsigned, v);
    auto r = __builtin_amdgcn_permlane16_swap(u, u, false, false);
    // r = {pair-low, pair-high} in some order; xor-all extracts the partner exactly.
    return __builtin_bit_cast(float, (unsigned)(r[0] ^ r[1] ^ u));
}
#else
__device__ __forceinline__ float xchg16f(float v) { return __shfl_xor(v, 16); }
#endif

#if __has_builtin(__builtin_amdgcn_permlane32_swap)
__device__ __forceinline__ float xchg32f(float v) {
    unsigned u = __builtin_bit_cast(unsigned, v);
    auto r = __builtin_amdgcn_permlane32_swap(u, u, false, false);
    return __builtin_bit_cast(float, (unsigned)(r[0] ^ r[1] ^ u));
}
#else
__device__ __forceinline__ float xchg32f(float v) { return __shfl_xor(v, 32); }
#endif

template<int M>
__device__ __forceinline__ float xlane(float v) {
    if constexpr (M == 1)       return dpp_mov<0xB1>(v);    // quad_perm [1,0,3,2]
    else if constexpr (M == 2)  return dpp_mov<0x4E>(v);    // quad_perm [2,3,0,1]
    else if constexpr (M == 8)  return dpp_mov<0x128>(v);   // row_ror:8
    else if constexpr (M == 16) return xchg16f(v);
    else if constexpr (M == 32) return xchg32f(v);
    else                        return __shfl_xor(v, M);    // M==4: ds_swizzle
}

// packed-spectrum pointwise: conj(G)[k] given Zk=Z[k], Zm=Z[N-k]
__device__ __forceinline__ float2 conjG(float2 Zk, float2 Zm) {
    float u = (Zk.x * Zk.x - Zk.y * Zk.y) - (Zm.x * Zm.x - Zm.y * Zm.y);
    float v = 2.f * (Zk.x * Zk.y + Zm.x * Zm.y);
    return make_float2(0.25f * v, 0.25f * u);
}

template<int M>
__device__ __forceinline__ void dstage(float2& x0, float2& x1, float2 w, int l) {
    float2 o0 = make_float2(xlane<M>(x0.x), xlane<M>(x0.y));
    float2 o1 = make_float2(xlane<M>(x1.x), xlane<M>(x1.y));
    if (l & M) {
        x0 = cmul(csub(o0, x0), w);
        x1 = cmul(csub(o1, x1), w);
    } else {
        x0 = cadd(x0, o0);
        x1 = cadd(x1, o1);
    }
}

// in-register 128-point DIF FFT across one wave; twiddles hoisted (lane-only).
// lane l holds positions l (x0), l+64 (x1); output: x0=X[rev7(l)], x1=X[rev7(l)+1]
__device__ __forceinline__ void dif128(float2& x0, float2& x1, const float2* tw, int l) {
    {   // stage m=64 (register-local)
        float2 a = x0, b = x1;
        x0 = cadd(a, b);
        x1 = cmul(csub(a, b), tw[0]);
    }
    dstage<32>(x0, x1, tw[1], l);
    dstage<16>(x0, x1, tw[2], l);
    dstage<8> (x0, x1, tw[3], l);
    dstage<4> (x0, x1, tw[4], l);
    dstage<2> (x0, x1, tw[5], l);
    dstage<1> (x0, x1, tw[6], l);
}

// ---- find the single nonzero (idx, sign) in each row of C1/C2 ----
// prefetch-1-ahead: issue step s+1's loads before waiting/checking step s,
// so straggler waves aren't serialized on per-step HBM latency.
__global__ void extract_sketch(const float* __restrict__ C1, const float* __restrict__ C2,
                               int* __restrict__ idx1, float* __restrict__ sgn1,
                               int* __restrict__ idx2, float* __restrict__ sgn2) {
    int gwave = (blockIdx.x * blockDim.x + threadIdx.x) >> 6;
    int lane = threadIdx.x & 63;
    if (gwave >= 2 * DIM) return;
    const float* row;
    int* idxp; float* sgnp; int d;
    if (gwave < DIM) { d = gwave;       row = C1 + (size_t)d * NFFT; idxp = idx1; sgnp = sgn1; }
    else             { d = gwave - DIM; row = C2 + (size_t)d * NFFT; idxp = idx2; sgnp = sgn2; }

    float4 v[4], n[4];
    auto load_step = [&](float4* dst, int step) {
        int off0 = step * 1024 + lane * 4;
        #pragma unroll
        for (int c = 0; c < 4; ++c) {
            int off = off0 + c * 256;
            dst[c] = (off < NFFT) ? *reinterpret_cast<const float4*>(row + off)
                                  : make_float4(0.f, 0.f, 0.f, 0.f);
        }
    };
    load_step(v, 0);
    for (int step = 0; step < 16; ++step) {
        if (step + 1 < 16) load_step(n, step + 1);   // in flight across the check
        int off0 = step * 1024 + lane * 4;
        bool found = false;
        #pragma unroll
        for (int c = 0; c < 4; ++c) {
            float4 w = v[c];
            if (w.x != 0.f || w.y != 0.f || w.z != 0.f || w.w != 0.f) {
                int off = off0 + c * 256;
                int j; float s;
                if (w.x != 0.f)      { j = 0; s = w.x; }
                else if (w.y != 0.f) { j = 1; s = w.y; }
                else if (w.z != 0.f) { j = 2; s = w.z; }
                else                 { j = 3; s = w.w; }
                idxp[d] = off + j;
                sgnp[d] = s;
                found = true;
            }
        }
        if (__any(found)) return;
        #pragma unroll
        for (int c = 0; c < 4; ++c) v[c] = n[c];
    }
}

// ---- K1: scatter + 125-point column FFTs (over n2) + inter-dim twiddle ----
// grid = 128 b x 4 quarters, 512 threads; writes U[b][k2*128 + n1] = S[n1][k2]*W_N^{n1*k2}
__global__ void __launch_bounds__(512) k1_colfft(
        const float* __restrict__ x1, const float* __restrict__ x2,
        const int* __restrict__ idx1, const float* __restrict__ sgn1,
        const int* __restrict__ idx2, const float* __restrict__ sgn2,
        float2* __restrict__ U) {
    __shared__ float2 S[32 * 125];
    const int b = blockIdx.x >> 2, q = blockIdx.x & 3;
    const int tid = threadIdx.x;

    for (int i = tid; i < 32 * 125; i += 512) S[i] = make_float2(0.f, 0.f);
    __syncthreads();

    const float* x1b = x1 + (size_t)b * DIM;
    const float* x2b = x2 + (size_t)b * DIM;
    for (int d = tid; d < DIM; d += 512) {
        int p1 = idx1[d]; int n1a = p1 & 127;
        if ((n1a >> 5) == q) atomicAdd(&S[(n1a & 31) * 125 + rev5_3(p1 >> 7)].x, sgn1[d] * x1b[d]);
        int p2 = idx2[d]; int n1b = p2 & 127;
        if ((n1b >> 5) == q) atomicAdd(&S[(n1b & 31) * 125 + rev5_3(p2 >> 7)].y, sgn2[d] * x2b[d]);
    }
    __syncthreads();

    const float C1_5 = 0.30901699437494742f, S1_5 = 0.95105651629515357f;
    const float C2_5 = -0.80901699437494745f, S2_5 = 0.58778525229247312f;
    const float2 w5tab[5] = { make_float2(1.f, 0.f),
                              make_float2(C1_5, -S1_5), make_float2(C2_5, -S2_5),
                              make_float2(C2_5,  S2_5), make_float2(C1_5,  S1_5) };
    #pragma unroll
    for (int s = 0; s < 3; ++s) {
        const int m = (s == 0) ? 1 : (s == 1) ? 5 : 25;
        const float angstep = -6.28318530717958647692f / (float)(5 * m);
        for (int task = tid; task < 32 * 25; task += 512) {
            int row = task / 25;
            int bf = task - row * 25;
            int t = bf % m, blk = bf / m;
            int base = row * 125 + blk * (5 * m) + t;
            float2 xv[5];
            #pragma unroll
            for (int r = 0; r < 5; ++r) xv[r] = S[base + r * m];
            if (m > 1) {
                float2 w1 = cis(angstep * (float)t);
                float2 w2 = cmul(w1, w1), w3 = cmul(w2, w1), w4 = cmul(w2, w2);
                xv[1] = cmul(xv[1], w1); xv[2] = cmul(xv[2], w2);
                xv[3] = cmul(xv[3], w3); xv[4] = cmul(xv[4], w4);
            }
            float2 y[5];
            #pragma unroll
            for (int qq = 0; qq < 5; ++qq) {
                float2 acc = xv[0];
                #pragma unroll
                for (int r = 1; r < 5; ++r) {
                    float2 t2 = cmul(xv[r], w5tab[(qq * r) % 5]);
                    acc.x += t2.x; acc.y += t2.y;
                }
                y[qq] = acc;
            }
            #pragma unroll
            for (int qq = 0; qq < 5; ++qq) S[base + qq * m] = y[qq];
        }
        __syncthreads();
    }

    const float ANGN = -6.28318530717958647692f / 16000.0f;
    const int n1base = q * 32;
    float2* Ub = U + (size_t)b * NFFT;
    for (int i = tid; i < 32 * 125; i += 512) {
        int n1l = i & 31, k2 = i >> 5;
        int n1 = n1base + n1l;
        Ub[k2 * 128 + n1] = cmul(S[n1l * 125 + k2], cis(ANGN * (float)(n1 * k2)));
    }
}

// ---- K2: per-wave column-pair, zero-LDS zero-barrier ----
// fwd 128-FFT -> pointwise (partner rows via shfl) -> inverse-start 128-FFT
// writes V[b][m1*128 + j1] = A[m1][j1] * W_N^{m1*j1}
__global__ void __launch_bounds__(256) k2_pair(const float2* __restrict__ U,
                                               float2* __restrict__ V) {
    const int w = threadIdx.x >> 6, l = threadIdx.x & 63;
    const int task = blockIdx.x * 4 + w;          // 2016*4 = 8064 = 128*63 exactly
    const int b = task / 63, cg = task - b * 63;
    const int c = cg, cm = cg ? 125 - cg : 0;
    const float2* Ub = U + (size_t)b * NFFT;
    const float PI_F = 3.14159265358979323846f;

    // hoisted dif128 twiddles (lane-only), reused across all 4 FFT calls
    float2 tw[7];
    tw[0] = cis(-PI_F / 64.0f * (float)l);
    {
        int m = 32;
        #pragma unroll
        for (int s = 1; s < 7; ++s, m >>= 1)
            tw[s] = cis(-PI_F / (float)m * (float)(l & (m - 1)));
    }

    float2 a0 = Ub[c * 128 + l], a1 = Ub[c * 128 + l + 64];
    dif128(a0, a1, tw, l);
    float2 b0, b1;
    if (cg) {
        b0 = Ub[cm * 128 + l]; b1 = Ub[cm * 128 + l + 64];
        dif128(b0, b1, tw, l);
    }

    const int e  = rev7(l);           // even; lane holds rows e, e+1
    const int lp = rev7(126 - e);     // holder lane of rows 126-e (reg0) / 127-e (reg1)

    // pointwise: partner of (col,row)=(c,r) is (125-c, 127-r) for c!=0
    float2 gA0, gA1, gB0, gB1;
    if (cg) {
        float2 zm0 = shfl2(b1, lp);   // Zcm[127-e]
        float2 zm1 = shfl2(b0, lp);   // Zcm[126-e]
        gA0 = conjG(a0, zm0);         // G'_c[e]
        gA1 = conjG(a1, zm1);         // G'_c[e+1]
        float2 ym0 = shfl2(a1, lp);   // Zc[127-e]
        float2 ym1 = shfl2(a0, lp);   // Zc[126-e]
        gB0 = conjG(b0, ym0);         // G'_cm[e]
        gB1 = conjG(b1, ym1);         // G'_cm[e+1]
    } else {
        int hz = rev7((128 - e) & 127);
        float2 zm0 = shfl2(a0, hz);   // Z0[(128-e)&127]
        float2 zm1 = shfl2(a1, lp);   // Z0[127-e]
        gA0 = conjG(a0, zm0);
        gA1 = conjG(a1, zm1);
        gB0 = gB1 = make_float2(0.f, 0.f);
    }

    // re-permute bit-reversed G' back to natural order for the inverse-start FFT:
    // G'[l] / G'[l+64] live as reg (l&1 ? 1 : 0) of lane q / q+1, q = rev7(l&~1)
    const int q = rev7(l & 62);
    const float ANGN = -6.28318530717958647692f / 16000.0f;
    float2* Vb = V + (size_t)b * NFFT;

    {
        float2 t00 = shfl2(gA0, q),     t10 = shfl2(gA1, q);
        float2 t01 = shfl2(gA0, q + 1), t11 = shfl2(gA1, q + 1);
        float2 p0 = (l & 1) ? t10 : t00;
        float2 p1 = (l & 1) ? t11 : t01;
        dif128(p0, p1, tw, l);
        p0 = cmul(p0, cis(ANGN * (float)(c * e)));
        p1 = cmul(p1, cis(ANGN * (float)(c * (e + 1))));
        *reinterpret_cast<float4*>(&Vb[c * 128 + e]) = make_float4(p0.x, p0.y, p1.x, p1.y);
    }
    if (cg) {
        float2 t00 = shfl2(gB0, q),     t10 = shfl2(gB1, q);
        float2 t01 = shfl2(gB0, q + 1), t11 = shfl2(gB1, q + 1);
        float2 p0 = (l & 1) ? t10 : t00;
        float2 p1 = (l & 1) ? t11 : t01;
        dif128(p0, p1, tw, l);
        p0 = cmul(p0, cis(ANGN * (float)(cm * e)));
        p1 = cmul(p1, cis(ANGN * (float)(cm * (e + 1))));
        *reinterpret_cast<float4*>(&Vb[cm * 128 + e]) = make_float4(p0.x, p0.y, p1.x, p1.y);
    }
}

// ---- K3: 125-point row FFTs (over m1) per (b, 16-wide j1 tile); real output ----
__global__ void __launch_bounds__(256) k3_rowfft(const float2* __restrict__ V,
                                                 float* __restrict__ out) {
    __shared__ float2 T[125 * TP];
    const int b = blockIdx.x >> 3, g = blockIdx.x & 7;
    const int j1base = g * 16, tid = threadIdx.x;
    const float2* Vb = V + (size_t)b * NFFT;

    for (int i = tid; i < 125 * 16; i += 256) {
        int m1 = i >> 4, j1l = i & 15;
        T[rev5_3(m1) * TP + j1l] = Vb[m1 * 128 + j1base + j1l];
    }
    __syncthreads();

    const float C1_5 = 0.30901699437494742f, S1_5 = 0.95105651629515357f;
    const float C2_5 = -0.80901699437494745f, S2_5 = 0.58778525229247312f;
    const float2 w5tab[5] = { make_float2(1.f, 0.f),
                              make_float2(C1_5, -S1_5), make_float2(C2_5, -S2_5),
                              make_float2(C2_5,  S2_5), make_float2(C1_5,  S1_5) };
    #pragma unroll
    for (int s = 0; s < 3; ++s) {
        const int m = (s == 0) ? 1 : (s == 1) ? 5 : 25;
        const float angstep = -6.28318530717958647692f / (float)(5 * m);
        for (int task = tid; task < 16 * 25; task += 256) {
            int bf = task >> 4;
            int j1l = task & 15;
            int t = bf % m, blk = bf / m;
            int base = (blk * (5 * m) + t) * TP + j1l;
            float2 xv[5];
            #pragma unroll
            for (int r = 0; r < 5; ++r) xv[r] = T[base + r * m * TP];
            if (m > 1) {
                float2 w1 = cis(angstep * (float)t);
                float2 w2 = cmul(w1, w1), w3 = cmul(w2, w1), w4 = cmul(w2, w2);
                xv[1] = cmul(xv[1], w1); xv[2] = cmul(xv[2], w2);
                xv[3] = cmul(xv[3], w3); xv[4] = cmul(xv[4], w4);
            }
            float2 y[5];
            #pragma unroll
            for (int qq = 0; qq < 5; ++qq) {
                float2 acc = xv[0];
                #pragma unroll
                for (int r = 1; r < 5; ++r) {
                    float2 t2 = cmul(xv[r], w5tab[(qq * r) % 5]);
                    acc.x += t2.x; acc.y += t2.y;
                }
                y[qq] = acc;
            }
            #pragma unroll
            for (int qq = 0; qq < 5; ++qq) T[base + qq * m * TP] = y[qq];
        }
        __syncthreads();
    }

    const float invN = 1.0f / (float)NFFT;
    float* outb = out + (size_t)b * NFFT;
    for (int i = tid; i < 125 * 16; i += 256) {
        int j2 = i >> 4, j1l = i & 15;
        outb[j1base + j1l + 128 * j2] = T[j2 * TP + j1l].x * invN;
    }
}

extern "C" void kernel_launch(void* const* d_in, const int* in_sizes, int n_in,
                              void* d_out, int out_size, void* d_ws, size_t ws_size,
                              hipStream_t stream) {
    (void)in_sizes; (void)n_in; (void)out_size; (void)ws_size;
    const float* x1 = (const float*)d_in[0];
    const float* x2 = (const float*)d_in[1];
    const float* C1 = (const float*)d_in[2];
    const float* C2 = (const float*)d_in[3];
    float* out = (float*)d_out;

    char* w = (char*)d_ws;
    int*    idx1 = (int*)  (w);                       // 8 KB
    float*  sgn1 = (float*)(w + 8192);                // 8 KB
    int*    idx2 = (int*)  (w + 16384);               // 8 KB
    float*  sgn2 = (float*)(w + 24576);               // 8 KB
    float2* U    = (float2*)(w + 32768);              // 16.384 MB
    float2* V    = (float2*)(w + 32768 + 16384000);   // 16.384 MB

    extract_sketch<<<(2 * DIM) / 4, 256, 0, stream>>>(C1, C2, idx1, sgn1, idx2, sgn2);
    k1_colfft     <<<BATCH * 4, 512, 0, stream>>>(x1, x2, idx1, sgn1, idx2, sgn2, U);
    k2_pair       <<<2016, 256, 0, stream>>>(U, V);
    k3_rowfft     <<<BATCH * 8, 256, 0, stream>>>(V, out);
}